// Round 16
// baseline (262.409 us; speedup 1.0000x reference)
//
#include <hip/hip_runtime.h>
#include <math.h>

#define NB 16
#define PP 2500
#define WWD 50
#define NANCH 22500
#define CIN 512
#define PRE 6000
#define POST 300
#define NW64 94          // ceil(6000/64): 94*64 = 6016 bits
#define NW32 188
#define NSEG 16          // segments per batch
#define SEG 1408         // per-segment rows (16*1408 = 22528 >= 22500)
#define SEGP 2048        // padded power-of-2
#define RUN 6016         // truncated run length (rank-safe > 6000)
#define NMST 512         // nms threads

// d_out float offsets (elements)
#define OFF_LOCS   0
#define OFF_SCORES 1440000
#define OFF_ROIS   2160000
#define OFF_ROIIX  2179200
#define OFF_ANCH   2184000

typedef unsigned long long u64;
typedef unsigned u32;

// async global->LDS (16B/lane). LDS dest is wave-uniform base + lane*16
// (m104/m108); global src is per-lane. No VGPR round-trip, no spill channel.
__device__ __forceinline__ void g2l16(const float* g, float* l) {
    __builtin_amdgcn_global_load_lds(
        (const __attribute__((address_space(1))) void*)g,
        (__attribute__((address_space(3))) void*)l, 16, 0, 0);
}

// ---- anchor for row r: f32-faithful to _enumerate_anchors (f64 base -> f32, f32 add) ----
__device__ inline float4 anchor_of(int r) {
    int p = r / 9, a = r - p * 9;
    int gy = p / WWD, gx = p - gy * WWD;
    int ri = a / 3, si = a - ri * 3;
    double ratio = (ri == 0) ? 0.5 : (ri == 1 ? 1.0 : 2.0);
    double scale = (si == 0) ? 8.0 : (si == 1 ? 16.0 : 32.0);
    double hh = 16.0 * scale * sqrt(ratio);
    double wd = 16.0 * scale * sqrt(1.0 / ratio);
    float by1 = (float)(8.0 - hh * 0.5);
    float bx1 = (float)(8.0 - wd * 0.5);
    float by2 = (float)(8.0 + hh * 0.5);
    float bx2 = (float)(8.0 + wd * 0.5);
    float sy = (float)gy * 16.0f, sx = (float)gx * 16.0f;
    return make_float4(sy + by1, sx + bx1, sy + by2, sx + bx2);
}

// ---- decode + clip + min-size: f32-faithful to _loc2bbox/_propose_one ----
__device__ inline float4 decode_box(const float* __restrict__ lp, float4 an,
                                    float ih, float iw, bool* ok) {
    float dy = lp[0], dx = lp[1], dh = lp[2], dw = lp[3];
    float h = an.z - an.x, w = an.w - an.y;
    float cy = an.x + 0.5f * h, cx = an.y + 0.5f * w;
    float ny = dy * h + cy, nx = dx * w + cx;
    float nh = expf(dh) * h, nw = expf(dw) * w;
    float y1 = fminf(fmaxf(ny - 0.5f * nh, 0.f), ih);
    float x1 = fminf(fmaxf(nx - 0.5f * nw, 0.f), iw);
    float y2 = fminf(fmaxf(ny + 0.5f * nh, 0.f), ih);
    float x2 = fminf(fmaxf(nx + 0.5f * nw, 0.f), iw);
    *ok = ((y2 - y1) >= 16.0f) && ((x2 - x1) >= 16.0f);
    return make_float4(y1, x1, y2, x2);
}

__device__ inline float iou_f32(float4 a, float4 b) {
    float ty1 = fmaxf(a.x, b.x), tx1 = fmaxf(a.y, b.y);
    float ty2 = fminf(a.z, b.z), tx2 = fminf(a.w, b.w);
    float inter = fmaxf(ty2 - ty1, 0.f) * fmaxf(tx2 - tx1, 0.f);
    float aa = (a.z - a.x) * (a.w - a.y);
    float ab = (b.z - b.x) * (b.w - b.y);
    return inter / fmaxf(aa + ab - inter, 1e-9f);
}

// ---------------- Kernel 1: relu + dual 1x1 conv ----------------
// r14 compute core + 3-buffer counted-vmcnt pipeline (T4, m201/m218):
// per tile {s_waitcnt vmcnt(2); raw s_barrier; issue stage(t+2); compute(t)}.
// Each stage = exactly 2 DMA issues/wave, so vmcnt(2) retires tile t's loads
// while t+1's stay in flight ACROSS the barrier (r15's __syncthreads drained
// vmcnt(0) every tile = full DMA latency serialized — the 93us was that).
// stage-after-barrier makes buf[(t+2)%3]=buf[(t-1)%3] overwrite race-free;
// per-wave vmcnt before barrier makes cross-wave LDS visibility sound.
// Final tile peeled with vmcnt(0). Staged data + accumulation order byte-
// identical to r14/r15 -> bit-identical outputs.
__global__ __launch_bounds__(256) void k_gemm(
    const float* __restrict__ x, const float* __restrict__ lw, const float* __restrict__ lb,
    const float* __restrict__ sw, const float* __restrict__ sb, float* __restrict__ out)
{
    __shared__ __align__(16) float wsL[3][64][16];   // 12 KB (rows 54-63 pad)
    __shared__ __align__(16) float xsL[3][16][64];   // 12 KB
    int bid = blockIdx.x;
    int b   = bid / 40;
    int pt  = bid % 40;
    int tid = threadIdx.x;
    int po  = tid & 63;
    int wv  = tid >> 6;
    int og  = __builtin_amdgcn_readfirstlane(wv);   // SGPR-uniform wave idx
    int ptbase = pt * 64;
    int p0  = ptbase + po;
    bool act0 = (p0 < PP);

    int o0  = og * 14;
    int cnt = (og == 3) ? 12 : 14;
    float bias[14];
#pragma unroll
    for (int k = 0; k < 14; ++k) {
        int o = o0 + k;
        int oc = (o < 54) ? o : 53;              // og=3 tail clamp (never stored)
        bias[k] = (oc < 36) ? lb[oc] : sb[oc - 36];
    }

    const float* xrow = x + (size_t)b * (CIN * PP);

    float acc0[14];
#pragma unroll
    for (int k = 0; k < 14; ++k) acc0[k] = 0.f;

    // ---- async stage: 1 x-chunk + 1 w-chunk per wave (2 vmcnt ops) ----
    auto stage_async = [&](int buf, int c0) {
        {   // x tile [16][64]: wave og covers floats og*256..og*256+255
            int fbase = og * 256 + po * 4;
            int cc = fbase >> 6;
            int xj = fbase & 63;
            int gpos = ptbase + xj;
            if (gpos > PP - 4) gpos = PP - 4;    // pt=39 tail (values unused)
            const float* gsrc = xrow + (size_t)(c0 + cc) * PP + gpos;
            float* ldst = &xsL[buf][0][0] + og * 256;
            g2l16(gsrc, ldst);
        }
        {   // w tile [64][16]: wave og covers rows og*16..og*16+15
            int fl = og * 256 + po * 4;
            int o = fl >> 4;
            int c4 = fl & 15;
            const float* gw = (o < 36) ? (lw + (size_t)o * CIN + c0 + c4)
                            : (o < 54) ? (sw + (size_t)(o - 36) * CIN + c0 + c4)
                                       : (lw + c4);  // safe dummy (rows 54-63)
            float* wdst = &wsL[buf][0][0] + og * 256;
            g2l16(gw, wdst);
        }
    };

    auto compute_tile = [&](int buf) {
#pragma unroll
        for (int g = 0; g < 4; ++g) {
            float x0[4];
#pragma unroll
            for (int u = 0; u < 4; ++u)
                x0[u] = fmaxf(xsL[buf][g * 4 + u][po], 0.f);
#pragma unroll
            for (int k = 0; k < 14; ++k) {
                float4 w4 = *reinterpret_cast<const float4*>(&wsL[buf][o0 + k][g * 4]);
                acc0[k] += x0[0] * w4.x;
                acc0[k] += x0[1] * w4.y;
                acc0[k] += x0[2] * w4.z;
                acc0[k] += x0[3] * w4.w;
            }
        }
    };

    stage_async(0, 0);
    stage_async(1, 16);

#pragma unroll 1
    for (int t = 0; t < 31; ++t) {
        asm volatile("s_waitcnt vmcnt(2)" ::: "memory");   // tile t landed; t+1 in flight
        __builtin_amdgcn_s_barrier();
        if (t + 2 < 32) stage_async((t + 2) % 3, (t + 2) * 16);
        compute_tile(t % 3);
    }
    asm volatile("s_waitcnt vmcnt(0)" ::: "memory");       // last tile landed
    __builtin_amdgcn_s_barrier();
    compute_tile(31 % 3);

    if (!act0) return;
#pragma unroll
    for (int k = 0; k < 14; ++k) {
        if (k < cnt) {
            int o = o0 + k;
            if (o < 36)
                out[(size_t)OFF_LOCS + ((size_t)b * PP + p0) * 36 + o] = acc0[k] + bias[k];
            else
                out[(size_t)OFF_SCORES + ((size_t)b * PP + p0) * 18 + (o - 36)] = acc0[k] + bias[k];
        }
    }
}

// ---------------- Kernel 2: per-segment key-gen + bitonic sort (desc) ----------------
__global__ __launch_bounds__(1024) void k_sort1(
    const float* __restrict__ out_ro, float* __restrict__ out, u64* __restrict__ runs,
    const int* __restrict__ imh_p, const int* __restrict__ imw_p)
{
    __shared__ u64 sk[SEGP];         // 16 KB
    int blk = blockIdx.x;
    int b = blk >> 4, s = blk & 15;
    int tid = threadIdx.x;
    int base = s * SEG;
    float ih = (float)imh_p[0], iw = (float)imw_p[0];

    for (int i = tid; i < SEGP; i += 1024) {
        int r = base + i;
        u64 key = 0ull;
        if (i < SEG && r < NANCH) {
            float4 an = anchor_of(r);
            if (b == 0) ((float4*)(out + OFF_ANCH))[r] = an;
            bool ok;
            (void)decode_box(out_ro + (size_t)OFF_LOCS + ((size_t)b * NANCH + r) * 4,
                             an, ih, iw, &ok);
            int p = r / 9, a = r - p * 9;
            const float* sp = out_ro + (size_t)OFF_SCORES + ((size_t)b * PP + p) * 18 + a * 2;
            float s0 = sp[0], s1 = sp[1];
            float mx = fmaxf(s0, s1);
            float e0 = expf(s0 - mx), e1 = expf(s1 - mx);
            float fg = e1 / (e0 + e1);
            float sc = ok ? fg : -INFINITY;
            u32 sb = __float_as_uint(sc);
            sb = (sb & 0x80000000u) ? ~sb : (sb | 0x80000000u);
            key = ((u64)sb << 32) | (u64)(u32)(NANCH - r);   // unique; idx-asc tiebreak
        }
        sk[i] = key;
    }
    __syncthreads();
    for (int kk = 2; kk <= SEGP; kk <<= 1) {
        for (int j = kk >> 1; j > 0; j >>= 1) {
            for (int i = tid; i < SEGP; i += 1024) {
                int ij = i ^ j;
                if (ij > i) {
                    u64 va = sk[i], vb = sk[ij];
                    bool up = ((i & kk) == 0);
                    if (up ? (va < vb) : (va > vb)) { sk[i] = vb; sk[ij] = va; }
                }
            }
            __syncthreads();
        }
    }
    u64* dst = runs + (size_t)blk * SEGP;
    for (int i = tid; i < SEGP; i += 1024) dst[i] = sk[i];
}

// ---------------- merge-path pairwise merge (descending, unique keys) ----------------
__device__ inline int mp_search(const u64* __restrict__ A, const u64* __restrict__ B,
                                int LA, int LB, int d) {
    int lo = max(0, d - LB), hi = min(d, LA);
    while (lo < hi) {
        int mid = (lo + hi) >> 1;
        if (A[mid] > B[d - 1 - mid]) lo = mid + 1; else hi = mid;
    }
    return lo;
}

__global__ __launch_bounds__(1024) void k_merge(
    const u64* __restrict__ in, u64* __restrict__ outk,
    int runLen, int pairsPerBatch, int outLen)
{
    int blk = blockIdx.x;
    int b = blk / pairsPerBatch, m = blk - b * pairsPerBatch;
    const u64* A = in + ((size_t)b * pairsPerBatch * 2 + 2 * m) * runLen;
    const u64* B = A + runLen;
    u64* C = outk + ((size_t)b * pairsPerBatch + m) * outLen;
    int E = (outLen + 1023) >> 10;
    int d0 = threadIdx.x * E;
    if (d0 >= outLen) return;
    int cnt = min(E, outLen - d0);
    int i = mp_search(A, B, runLen, runLen, d0);
    int j = d0 - i;
    for (int e = 0; e < cnt; ++e) {
        u64 va = (i < runLen) ? A[i] : 0ull;
        u64 vb = (j < runLen) ? B[j] : 0ull;
        bool takeA = (j >= runLen) || ((i < runLen) && (va > vb));
        C[d0 + e] = takeA ? va : vb;
        if (takeA) ++i; else ++j;
    }
}

// ---------------- final merge + emit boxes (top-6000, sorted) ----------------
__global__ __launch_bounds__(1024) void k_merge_emit(
    const u64* __restrict__ in, const float* __restrict__ out_ro,
    float* __restrict__ topBoxes, u32* __restrict__ topValid,
    const int* __restrict__ imh_p, const int* __restrict__ imw_p)
{
    int b = blockIdx.x;
    const u64* A = in + (size_t)b * 2 * RUN;
    const u64* B = A + RUN;
    float ih = (float)imh_p[0], iw = (float)imw_p[0];
    int E = (PRE + 1023) >> 10;   // 6
    int d0 = threadIdx.x * E;
    if (d0 >= PRE) return;
    int cnt = min(E, PRE - d0);
    int i = mp_search(A, B, RUN, RUN, d0);
    int j = d0 - i;
    for (int e = 0; e < cnt; ++e) {
        u64 va = (i < RUN) ? A[i] : 0ull;
        u64 vb = (j < RUN) ? B[j] : 0ull;
        bool takeA = (j >= RUN) || ((i < RUN) && (va > vb));
        u64 key = takeA ? va : vb;
        if (takeA) ++i; else ++j;
        int d = d0 + e;
        bool valid = (key >> 63) != 0ull;
        int idx = valid ? (NANCH - (int)(key & 0xFFFFFFFFull)) : 0;
        bool ok;
        float4 an = anchor_of(idx);
        float4 bx = decode_box(out_ro + (size_t)OFF_LOCS + ((size_t)b * NANCH + idx) * 4,
                               an, ih, iw, &ok);
        ((float4*)topBoxes)[(size_t)b * PRE + d] = bx;
        topValid[(size_t)b * PRE + d] = valid ? 1u : 0u;
    }
}

// ---------------- Kernel 4: lazy/JIT greedy NMS (512 thr) ----------------
__global__ __launch_bounds__(NMST) void k_nms(const float* __restrict__ topBoxes,
                                              const u32* __restrict__ topValid,
                                              float* __restrict__ out)
{
    __shared__ float4 chunkB[64];
    __shared__ float4 keptB[POST];
    __shared__ u32 sup[NW32];
    __shared__ int s_nk;
    __shared__ int s_stop;
    int b = blockIdx.x, tid = threadIdx.x;
    int wave = tid >> 6, lane = tid & 63;      // 8 waves
    const float4* tb = (const float4*)topBoxes + (size_t)b * PRE;

    for (int i = tid; i < NW32; i += NMST) sup[i] = 0u;
    if (tid == 0) { s_nk = 0; s_stop = 0; }
    __syncthreads();
    for (int r = tid; r < PRE; r += NMST)
        if (!topValid[(size_t)b * PRE + r]) atomicOr(&sup[r >> 5], 1u << (r & 31));
    if (tid == 0) atomicOr(&sup[187], 0xFFFF0000u);   // bits 6000..6015 invalid
    __syncthreads();

    for (int c = 0; c < NW64; ++c) {
        int base = c * 64;
        if (tid < 64)
            chunkB[tid] = (base + tid < PRE) ? tb[base + tid]
                                             : make_float4(0.f, 0.f, 0.f, 0.f);
        // ---- JIT: suppress this chunk's rows vs kept list so far ----
        int nk0 = s_nk;
        bool s = false;
        if (nk0 > 0 && base + lane < PRE) {
            float4 bj = tb[base + lane];
            for (int t = wave; t < nk0; t += 8)
                s |= iou_f32(keptB[t], bj) > 0.7f;
        }
        u64 bal = __ballot(s);
        if (lane == 0 && bal) {
            atomicOr(&sup[2 * c], (u32)bal);
            atomicOr(&sup[2 * c + 1], (u32)(bal >> 32));
        }
        __syncthreads();
        // ---- phase A: wave 0 resolves chunk serially ----
        if (wave == 0) {
            u64 avail = ~(((u64)sup[2 * c + 1] << 32) | (u64)sup[2 * c]);
            float4 myB = chunkB[lane];
            int nkl = s_nk;
            while (avail && nkl < POST) {
                int i = __builtin_ctzll(avail);
                float4 bi = chunkB[i];
                if (lane == 0) keptB[nkl] = bi;
                nkl++;
                bool ss = iou_f32(bi, myB) > 0.7f;
                u64 bb = __ballot(ss);
                avail &= ~((1ull << i) | bb);
            }
            if (lane == 0) { s_nk = nkl; if (nkl >= POST) s_stop = 1; }
        }
        __syncthreads();
        if (s_stop) break;
    }

    __syncthreads();
    int nk = min(s_nk, POST);
    for (int r = tid; r < POST; r += NMST) {
        float4 v = make_float4(0.f, 0.f, 0.f, 0.f);
        if (r < nk) v = keptB[r];
        ((float4*)(out + OFF_ROIS))[(size_t)b * POST + r] = v;
        out[(size_t)OFF_ROIIX + (size_t)b * POST + r] = (float)b;
    }
}

// ---------------- launch ----------------
extern "C" void kernel_launch(void* const* d_in, const int* in_sizes, int n_in,
                              void* d_out, int out_size, void* d_ws, size_t ws_size,
                              hipStream_t stream) {
    const float* x  = (const float*)d_in[0];
    const int* imh  = (const int*)d_in[1];
    const int* imw  = (const int*)d_in[2];
    // d_in[3]=conv1_w, d_in[4]=conv1_b: unused by the reference
    const float* sw = (const float*)d_in[5];
    const float* sb = (const float*)d_in[6];
    const float* lw = (const float*)d_in[7];
    const float* lb = (const float*)d_in[8];
    float* out = (float*)d_out;
    char* wsb = (char*)d_ws;

    u64*   runs0    = (u64*)(wsb);                     // 16*16*2048*8 = 4,194,304 B
    u64*   runs1    = (u64*)(wsb + 4194304);           // 16*8*4096*8  = 4,194,304 B
    u64*   runs2    = (u64*)(wsb + 8388608);           // 16*4*6016*8  = 3,080,192 B
    u64*   runs3    = (u64*)(wsb + 11468800);          // 16*2*6016*8  = 1,540,096 B
    float* topBoxes = (float*)(wsb + 13008896);        // 16*6000*16   = 1,536,000 B
    u32*   topValid = (u32*)(wsb + 14544896);          // 16*6000*4    =   384,000 B

    hipLaunchKernelGGL(k_gemm, dim3(NB * 40), dim3(256), 0, stream,
                       x, lw, lb, sw, sb, out);
    hipLaunchKernelGGL(k_sort1, dim3(NB * NSEG), dim3(1024), 0, stream,
                       out, out, runs0, imh, imw);
    hipLaunchKernelGGL(k_merge, dim3(NB * 8), dim3(1024), 0, stream,
                       runs0, runs1, SEGP, 8, 4096);
    hipLaunchKernelGGL(k_merge, dim3(NB * 4), dim3(1024), 0, stream,
                       runs1, runs2, 4096, 4, RUN);
    hipLaunchKernelGGL(k_merge, dim3(NB * 2), dim3(1024), 0, stream,
                       runs2, runs3, RUN, 2, RUN);
    hipLaunchKernelGGL(k_merge_emit, dim3(NB), dim3(1024), 0, stream,
                       runs3, out, topBoxes, topValid, imh, imw);
    hipLaunchKernelGGL(k_nms, dim3(NB), dim3(NMST), 0, stream,
                       topBoxes, topValid, out);
}

// Round 17
// 232.339 us; speedup vs baseline: 1.1294x; 1.1294x over previous
//
#include <hip/hip_runtime.h>
#include <math.h>

#define NB 16
#define PP 2500
#define WWD 50
#define NANCH 22500
#define CIN 512
#define PRE 6000
#define POST 300
#define NW64 94          // ceil(6000/64): 94*64 = 6016 bits
#define NW32 188
#define NSEG 16          // segments per batch
#define SEG 1408         // per-segment rows (16*1408 = 22528 >= 22500)
#define SEGP 2048        // padded power-of-2
#define RUN 6016         // truncated run length (rank-safe > 6000)
#define NMST 512         // nms threads

// d_out float offsets (elements)
#define OFF_LOCS   0
#define OFF_SCORES 1440000
#define OFF_ROIS   2160000
#define OFF_ROIIX  2179200
#define OFF_ANCH   2184000

typedef unsigned long long u64;
typedef unsigned u32;

// async global->LDS (16B/lane). LDS dest is wave-uniform base + lane*16
// (m104/m108); global src is per-lane. No VGPR round-trip, no spill channel.
__device__ __forceinline__ void g2l16(const float* g, float* l) {
    __builtin_amdgcn_global_load_lds(
        (const __attribute__((address_space(1))) void*)g,
        (__attribute__((address_space(3))) void*)l, 16, 0, 0);
}

// ---- anchor for row r: f32-faithful to _enumerate_anchors (f64 base -> f32, f32 add) ----
__device__ inline float4 anchor_of(int r) {
    int p = r / 9, a = r - p * 9;
    int gy = p / WWD, gx = p - gy * WWD;
    int ri = a / 3, si = a - ri * 3;
    double ratio = (ri == 0) ? 0.5 : (ri == 1 ? 1.0 : 2.0);
    double scale = (si == 0) ? 8.0 : (si == 1 ? 16.0 : 32.0);
    double hh = 16.0 * scale * sqrt(ratio);
    double wd = 16.0 * scale * sqrt(1.0 / ratio);
    float by1 = (float)(8.0 - hh * 0.5);
    float bx1 = (float)(8.0 - wd * 0.5);
    float by2 = (float)(8.0 + hh * 0.5);
    float bx2 = (float)(8.0 + wd * 0.5);
    float sy = (float)gy * 16.0f, sx = (float)gx * 16.0f;
    return make_float4(sy + by1, sx + bx1, sy + by2, sx + bx2);
}

// ---- decode + clip + min-size: f32-faithful to _loc2bbox/_propose_one ----
__device__ inline float4 decode_box(const float* __restrict__ lp, float4 an,
                                    float ih, float iw, bool* ok) {
    float dy = lp[0], dx = lp[1], dh = lp[2], dw = lp[3];
    float h = an.z - an.x, w = an.w - an.y;
    float cy = an.x + 0.5f * h, cx = an.y + 0.5f * w;
    float ny = dy * h + cy, nx = dx * w + cx;
    float nh = expf(dh) * h, nw = expf(dw) * w;
    float y1 = fminf(fmaxf(ny - 0.5f * nh, 0.f), ih);
    float x1 = fminf(fmaxf(nx - 0.5f * nw, 0.f), iw);
    float y2 = fminf(fmaxf(ny + 0.5f * nh, 0.f), ih);
    float x2 = fminf(fmaxf(nx + 0.5f * nw, 0.f), iw);
    *ok = ((y2 - y1) >= 16.0f) && ((x2 - x1) >= 16.0f);
    return make_float4(y1, x1, y2, x2);
}

__device__ inline float iou_f32(float4 a, float4 b) {
    float ty1 = fmaxf(a.x, b.x), tx1 = fmaxf(a.y, b.y);
    float ty2 = fminf(a.z, b.z), tx2 = fminf(a.w, b.w);
    float inter = fmaxf(ty2 - ty1, 0.f) * fmaxf(tx2 - tx1, 0.f);
    float aa = (a.z - a.x) * (a.w - a.y);
    float ab = (b.z - b.x) * (b.w - b.y);
    return inter / fmaxf(aa + ab - inter, 1e-9f);
}

// ---------------- Kernel 1: relu + dual 1x1 conv (r15 EXACT — 93.4us proven; ----------------
// r16's counted-vmcnt 3-buffer variant regressed to 123us: VGPR 56->124,
// occupancy 22->14% — inline-asm pipeline defeated compiler scheduling.)
__global__ __launch_bounds__(256) void k_gemm(
    const float* __restrict__ x, const float* __restrict__ lw, const float* __restrict__ lb,
    const float* __restrict__ sw, const float* __restrict__ sb, float* __restrict__ out)
{
    __shared__ __align__(16) float wsL[2][64][16];   // 8 KB (rows 54-63 pad)
    __shared__ __align__(16) float xsL[2][16][64];   // 8 KB
    int bid = blockIdx.x;
    int b   = bid / 40;
    int pt  = bid % 40;
    int tid = threadIdx.x;
    int po  = tid & 63;
    int wv  = tid >> 6;
    int og  = __builtin_amdgcn_readfirstlane(wv);   // SGPR-uniform wave idx
    int ptbase = pt * 64;
    int p0  = ptbase + po;
    bool act0 = (p0 < PP);

    int o0  = og * 14;
    int cnt = (og == 3) ? 12 : 14;
    float bias[14];
#pragma unroll
    for (int k = 0; k < 14; ++k) {
        int o = o0 + k;
        int oc = (o < 54) ? o : 53;              // og=3 tail clamp (never stored)
        bias[k] = (oc < 36) ? lb[oc] : sb[oc - 36];
    }

    const float* xrow = x + (size_t)b * (CIN * PP);

    float acc0[14];
#pragma unroll
    for (int k = 0; k < 14; ++k) acc0[k] = 0.f;

    auto stage_async = [&](int buf, int c0) {
        {   // x tile [16][64]: wave og covers floats og*256..og*256+255
            int fbase = og * 256 + po * 4;
            int cc = fbase >> 6;
            int xj = fbase & 63;
            int gpos = ptbase + xj;
            if (gpos > PP - 4) gpos = PP - 4;    // pt=39 tail (values unused)
            const float* gsrc = xrow + (size_t)(c0 + cc) * PP + gpos;
            float* ldst = &xsL[buf][0][0] + og * 256;
            g2l16(gsrc, ldst);
        }
        {   // w tile [64][16]: wave og covers rows og*16..og*16+15
            int fl = og * 256 + po * 4;
            int o = fl >> 4;
            int c4 = fl & 15;
            const float* gw = (o < 36) ? (lw + (size_t)o * CIN + c0 + c4)
                            : (o < 54) ? (sw + (size_t)(o - 36) * CIN + c0 + c4)
                                       : (lw + c4);  // safe dummy (rows 54-63)
            float* wdst = &wsL[buf][0][0] + og * 256;
            g2l16(gw, wdst);
        }
    };

    stage_async(0, 0);
    __syncthreads();

#pragma unroll 1
    for (int t = 0; t < 32; ++t) {
        int cur = t & 1;
        if (t + 1 < 32) stage_async(cur ^ 1, (t + 1) * 16);
#pragma unroll
        for (int g = 0; g < 4; ++g) {
            float x0[4];
#pragma unroll
            for (int u = 0; u < 4; ++u)
                x0[u] = fmaxf(xsL[cur][g * 4 + u][po], 0.f);
#pragma unroll
            for (int k = 0; k < 14; ++k) {
                float4 w4 = *reinterpret_cast<const float4*>(&wsL[cur][o0 + k][g * 4]);
                acc0[k] += x0[0] * w4.x;
                acc0[k] += x0[1] * w4.y;
                acc0[k] += x0[2] * w4.z;
                acc0[k] += x0[3] * w4.w;
            }
        }
        __syncthreads();
    }

    if (!act0) return;
#pragma unroll
    for (int k = 0; k < 14; ++k) {
        if (k < cnt) {
            int o = o0 + k;
            if (o < 36)
                out[(size_t)OFF_LOCS + ((size_t)b * PP + p0) * 36 + o] = acc0[k] + bias[k];
            else
                out[(size_t)OFF_SCORES + ((size_t)b * PP + p0) * 18 + (o - 36)] = acc0[k] + bias[k];
        }
    }
}

// ---------------- Kernel 2: per-segment key-gen + bitonic sort (desc) ----------------
__global__ __launch_bounds__(1024) void k_sort1(
    const float* __restrict__ out_ro, float* __restrict__ out, u64* __restrict__ runs,
    const int* __restrict__ imh_p, const int* __restrict__ imw_p)
{
    __shared__ u64 sk[SEGP];         // 16 KB
    int blk = blockIdx.x;
    int b = blk >> 4, s = blk & 15;
    int tid = threadIdx.x;
    int base = s * SEG;
    float ih = (float)imh_p[0], iw = (float)imw_p[0];

    for (int i = tid; i < SEGP; i += 1024) {
        int r = base + i;
        u64 key = 0ull;
        if (i < SEG && r < NANCH) {
            float4 an = anchor_of(r);
            if (b == 0) ((float4*)(out + OFF_ANCH))[r] = an;
            bool ok;
            (void)decode_box(out_ro + (size_t)OFF_LOCS + ((size_t)b * NANCH + r) * 4,
                             an, ih, iw, &ok);
            int p = r / 9, a = r - p * 9;
            const float* sp = out_ro + (size_t)OFF_SCORES + ((size_t)b * PP + p) * 18 + a * 2;
            float s0 = sp[0], s1 = sp[1];
            float mx = fmaxf(s0, s1);
            float e0 = expf(s0 - mx), e1 = expf(s1 - mx);
            float fg = e1 / (e0 + e1);
            float sc = ok ? fg : -INFINITY;
            u32 sb = __float_as_uint(sc);
            sb = (sb & 0x80000000u) ? ~sb : (sb | 0x80000000u);
            key = ((u64)sb << 32) | (u64)(u32)(NANCH - r);   // unique; idx-asc tiebreak
        }
        sk[i] = key;
    }
    __syncthreads();
    for (int kk = 2; kk <= SEGP; kk <<= 1) {
        for (int j = kk >> 1; j > 0; j >>= 1) {
            for (int i = tid; i < SEGP; i += 1024) {
                int ij = i ^ j;
                if (ij > i) {
                    u64 va = sk[i], vb = sk[ij];
                    bool up = ((i & kk) == 0);
                    if (up ? (va < vb) : (va > vb)) { sk[i] = vb; sk[ij] = va; }
                }
            }
            __syncthreads();
        }
    }
    u64* dst = runs + (size_t)blk * SEGP;
    for (int i = tid; i < SEGP; i += 1024) dst[i] = sk[i];
}

// ---------------- merge-path search (descending, unique keys) ----------------
__device__ inline int mp_search(const u64* A, const u64* B, int LA, int LB, int d) {
    int lo = max(0, d - LB), hi = min(d, LA);
    while (lo < hi) {
        int mid = (lo + hi) >> 1;
        if (A[mid] > B[d - 1 - mid]) lo = mid + 1; else hi = mid;
    }
    return lo;
}

// serial merge of [d0, d0+cnt) from runs A,B (lengths LA,LB) -> dst (generic ptrs)
__device__ inline void mp_merge_seg(const u64* A, const u64* B, int LA, int LB,
                                    int d0, int cnt, u64* dst) {
    int i = mp_search(A, B, LA, LB, d0);
    int j = d0 - i;
    for (int e = 0; e < cnt; ++e) {
        u64 va = (i < LA) ? A[i] : 0ull;
        u64 vb = (j < LB) ? B[j] : 0ull;
        bool takeA = (j >= LB) || ((i < LA) && (va > vb));
        dst[d0 + e] = takeA ? va : vb;
        if (takeA) ++i; else ++j;
    }
}

// ---------------- Kernel 3a: fused merge levels 1+2 ----------------
// Block (b,m): 4 runs of 2048 -> two LDS 4096-runs -> one global 6016-run.
// Removes one launch + an 8MB global round-trip vs separate levels.
__global__ __launch_bounds__(1024) void k_mergeA(
    const u64* __restrict__ in, u64* __restrict__ outk)
{
    __shared__ u64 bufA[4096];   // 32 KB
    __shared__ u64 bufB[4096];   // 32 KB
    int blk = blockIdx.x;
    int b = blk >> 2, m = blk & 3;
    int tid = threadIdx.x;
    const u64* s0 = in + ((size_t)b * NSEG + 4 * m) * SEGP;
    const u64* s1 = s0 + SEGP;
    const u64* s2 = s1 + SEGP;
    const u64* s3 = s2 + SEGP;
    // level 1: two independent merges into disjoint LDS buffers (no barrier between)
    mp_merge_seg(s0, s1, SEGP, SEGP, tid * 4, 4, bufA);
    mp_merge_seg(s2, s3, SEGP, SEGP, tid * 4, 4, bufB);
    __syncthreads();
    // level 2: LDS-sourced merge, truncated to RUN (rank-safe)
    int d0 = tid * 6;
    if (d0 < RUN)
        mp_merge_seg(bufA, bufB, 4096, 4096, d0, min(6, RUN - d0),
                     outk + ((size_t)b * 4 + m) * RUN);
}

// ---------------- Kernel 3b: fused merge levels 3+4 + box emit ----------------
// Block b: 4 runs of 6016 -> two LDS 6016-runs -> final merged top-6000 with
// fused re-decode. Removes one launch + round-trip vs separate level+emit.
__global__ __launch_bounds__(1024) void k_mergeB_emit(
    const u64* __restrict__ in, const float* __restrict__ out_ro,
    float* __restrict__ topBoxes, u32* __restrict__ topValid,
    const int* __restrict__ imh_p, const int* __restrict__ imw_p)
{
    __shared__ u64 bufA[RUN];    // 47 KB
    __shared__ u64 bufB[RUN];    // 47 KB
    int b = blockIdx.x;
    int tid = threadIdx.x;
    const u64* r0 = in + (size_t)b * 4 * RUN;
    const u64* r1 = r0 + RUN;
    const u64* r2 = r1 + RUN;
    const u64* r3 = r2 + RUN;
    int d0 = tid * 6;
    if (d0 < RUN) {
        int c = min(6, RUN - d0);
        mp_merge_seg(r0, r1, RUN, RUN, d0, c, bufA);
        mp_merge_seg(r2, r3, RUN, RUN, d0, c, bufB);
    }
    __syncthreads();
    // final merge + emit top-6000 (sorted), fused decode
    float ih = (float)imh_p[0], iw = (float)imw_p[0];
    if (d0 >= PRE) return;
    int cnt = min(6, PRE - d0);
    int i = mp_search(bufA, bufB, RUN, RUN, d0);
    int j = d0 - i;
    for (int e = 0; e < cnt; ++e) {
        u64 va = (i < RUN) ? bufA[i] : 0ull;
        u64 vb = (j < RUN) ? bufB[j] : 0ull;
        bool takeA = (j >= RUN) || ((i < RUN) && (va > vb));
        u64 key = takeA ? va : vb;
        if (takeA) ++i; else ++j;
        int d = d0 + e;
        bool valid = (key >> 63) != 0ull;
        int idx = valid ? (NANCH - (int)(key & 0xFFFFFFFFull)) : 0;
        bool ok;
        float4 an = anchor_of(idx);
        float4 bx = decode_box(out_ro + (size_t)OFF_LOCS + ((size_t)b * NANCH + idx) * 4,
                               an, ih, iw, &ok);
        ((float4*)topBoxes)[(size_t)b * PRE + d] = bx;
        topValid[(size_t)b * PRE + d] = valid ? 1u : 0u;
    }
}

// ---------------- Kernel 4: lazy/JIT greedy NMS (512 thr) ----------------
__global__ __launch_bounds__(NMST) void k_nms(const float* __restrict__ topBoxes,
                                              const u32* __restrict__ topValid,
                                              float* __restrict__ out)
{
    __shared__ float4 chunkB[64];
    __shared__ float4 keptB[POST];
    __shared__ u32 sup[NW32];
    __shared__ int s_nk;
    __shared__ int s_stop;
    int b = blockIdx.x, tid = threadIdx.x;
    int wave = tid >> 6, lane = tid & 63;      // 8 waves
    const float4* tb = (const float4*)topBoxes + (size_t)b * PRE;

    for (int i = tid; i < NW32; i += NMST) sup[i] = 0u;
    if (tid == 0) { s_nk = 0; s_stop = 0; }
    __syncthreads();
    for (int r = tid; r < PRE; r += NMST)
        if (!topValid[(size_t)b * PRE + r]) atomicOr(&sup[r >> 5], 1u << (r & 31));
    if (tid == 0) atomicOr(&sup[187], 0xFFFF0000u);   // bits 6000..6015 invalid
    __syncthreads();

    for (int c = 0; c < NW64; ++c) {
        int base = c * 64;
        if (tid < 64)
            chunkB[tid] = (base + tid < PRE) ? tb[base + tid]
                                             : make_float4(0.f, 0.f, 0.f, 0.f);
        // ---- JIT: suppress this chunk's rows vs kept list so far ----
        int nk0 = s_nk;
        bool s = false;
        if (nk0 > 0 && base + lane < PRE) {
            float4 bj = tb[base + lane];
            for (int t = wave; t < nk0; t += 8)
                s |= iou_f32(keptB[t], bj) > 0.7f;
        }
        u64 bal = __ballot(s);
        if (lane == 0 && bal) {
            atomicOr(&sup[2 * c], (u32)bal);
            atomicOr(&sup[2 * c + 1], (u32)(bal >> 32));
        }
        __syncthreads();
        // ---- phase A: wave 0 resolves chunk serially ----
        if (wave == 0) {
            u64 avail = ~(((u64)sup[2 * c + 1] << 32) | (u64)sup[2 * c]);
            float4 myB = chunkB[lane];
            int nkl = s_nk;
            while (avail && nkl < POST) {
                int i = __builtin_ctzll(avail);
                float4 bi = chunkB[i];
                if (lane == 0) keptB[nkl] = bi;
                nkl++;
                bool ss = iou_f32(bi, myB) > 0.7f;
                u64 bb = __ballot(ss);
                avail &= ~((1ull << i) | bb);
            }
            if (lane == 0) { s_nk = nkl; if (nkl >= POST) s_stop = 1; }
        }
        __syncthreads();
        if (s_stop) break;
    }

    __syncthreads();
    int nk = min(s_nk, POST);
    for (int r = tid; r < POST; r += NMST) {
        float4 v = make_float4(0.f, 0.f, 0.f, 0.f);
        if (r < nk) v = keptB[r];
        ((float4*)(out + OFF_ROIS))[(size_t)b * POST + r] = v;
        out[(size_t)OFF_ROIIX + (size_t)b * POST + r] = (float)b;
    }
}

// ---------------- launch ----------------
extern "C" void kernel_launch(void* const* d_in, const int* in_sizes, int n_in,
                              void* d_out, int out_size, void* d_ws, size_t ws_size,
                              hipStream_t stream) {
    const float* x  = (const float*)d_in[0];
    const int* imh  = (const int*)d_in[1];
    const int* imw  = (const int*)d_in[2];
    // d_in[3]=conv1_w, d_in[4]=conv1_b: unused by the reference
    const float* sw = (const float*)d_in[5];
    const float* sb = (const float*)d_in[6];
    const float* lw = (const float*)d_in[7];
    const float* lb = (const float*)d_in[8];
    float* out = (float*)d_out;
    char* wsb = (char*)d_ws;

    u64*   runs0    = (u64*)(wsb);                     // 16*16*2048*8 = 4,194,304 B
    u64*   runs1    = (u64*)(wsb + 4194304);           // 16*4*6016*8  = 3,080,192 B
    float* topBoxes = (float*)(wsb + 7274496);         // 16*6000*16   = 1,536,000 B
    u32*   topValid = (u32*)(wsb + 8810496);           // 16*6000*4    =   384,000 B

    hipLaunchKernelGGL(k_gemm, dim3(NB * 40), dim3(256), 0, stream,
                       x, lw, lb, sw, sb, out);
    hipLaunchKernelGGL(k_sort1, dim3(NB * NSEG), dim3(1024), 0, stream,
                       out, out, runs0, imh, imw);
    hipLaunchKernelGGL(k_mergeA, dim3(NB * 4), dim3(1024), 0, stream,
                       runs0, runs1);
    hipLaunchKernelGGL(k_mergeB_emit, dim3(NB), dim3(1024), 0, stream,
                       runs1, out, topBoxes, topValid, imh, imw);
    hipLaunchKernelGGL(k_nms, dim3(NB), dim3(NMST), 0, stream,
                       topBoxes, topValid, out);
}